// Round 4
// baseline (2252.543 us; speedup 1.0000x reference)
//
#include <hip/hip_runtime.h>
#include <hip/hip_bf16.h>
#include <math.h>

namespace {

constexpr int SEQ    = 64;
constexpr int DINNER = 1024;
constexpr int DFF    = 16;
constexpr int DTRANK = 32;
constexpr unsigned NBLK = 512;

typedef __attribute__((ext_vector_type(8))) short short8;
typedef __attribute__((ext_vector_type(4))) float f32x4;
typedef __attribute__((address_space(3))) unsigned int lds_u32_t;
typedef __attribute__((address_space(1))) unsigned int glb_u32_t;

__device__ __forceinline__ float sigm(float x) { return 1.f / (1.f + __expf(-x)); }
__device__ __forceinline__ short f2b(float v) {
    __hip_bfloat16 h = __float2bfloat16(v);
    return *(short*)&h;
}

enum { EPI_NONE = 0, EPI_SPATIAL1, EPI_BIAS_MUL, EPI_ADD };

union LdsU {
    struct { short A[64 * 32]; short B[64 * 32]; } gm;            // bf16 GEMM tiles (8 KB)
    struct { float As[16][68]; float Bs[16][68]; } g32;           // fp32 dt GEMM (8.7 KB)
    struct { float Bm[SEQ][DFF]; float Cm[SEQ][DFF]; } sc;        // scan B/C (8 KB)
    struct { float4 Us[256]; float4 Vs[256]; float ins[256]; float4 tpart[4]; } co; // coeffs (9.3 KB)
};

struct P {
    const float *inputs, *lin1_b, *lin2_b, *gate_b, *sp_norm_w;
    const float *conv_w, *conv_b, *dt_proj_w, *dt_proj_b, *A_log, *Dvec;
    const float *blk_norm_w, *post_norm_w;
    const float *lin1_w, *gate_w, *lin2_w, *in_proj_w, *x_proj_w, *out_proj_w, *proj_w;
    float *h, *xr, *xc, *delta, *xdbl, *g;
    short *inputsb, *hnb, *xcb, *yb, *h1b;
    short *wlin1b, *wgateb, *wlin2b, *winpb, *wxpb, *woutpb, *wprojb;
    float *preds, *coeffs;
    unsigned *bar;   // [0]=count, [1]=generation (memset to 0 each launch)
};

// ---- manual grid barrier: device-scope atomics + agent fences (G12/G16).
// Requires all NBLK blocks co-resident: __launch_bounds__(256,2) -> VGPR<=256
// -> 8 waves/CU -> 2 blocks/CU x 256 CUs = 512. Plain launch, graph-safe.
__device__ __forceinline__ void gbar(unsigned* cnt, unsigned* gen) {
    __syncthreads();
    if (threadIdx.x == 0) {
        __threadfence();   // release: write back this XCD's caches
        const unsigned g = __hip_atomic_load(gen, __ATOMIC_RELAXED, __HIP_MEMORY_SCOPE_AGENT);
        const unsigned a = __hip_atomic_fetch_add(cnt, 1u, __ATOMIC_RELAXED, __HIP_MEMORY_SCOPE_AGENT);
        if (a == NBLK - 1u) {
            __hip_atomic_store(cnt, 0u, __ATOMIC_RELAXED, __HIP_MEMORY_SCOPE_AGENT);
            __hip_atomic_store(gen, g + 1u, __ATOMIC_RELEASE, __HIP_MEMORY_SCOPE_AGENT);
        } else {
            while (__hip_atomic_load(gen, __ATOMIC_RELAXED, __HIP_MEMORY_SCOPE_AGENT) == g)
                __builtin_amdgcn_s_sleep(4);
        }
        __threadfence();   // acquire: invalidate stale lines before next phase reads
    }
    __syncthreads();
}

// ---- bf16 MFMA GEMM tile: C(64x64) = epi(A[tm] @ W[tn]^T), BK=32, 4 waves (2x2)
template <int EPI, int OUTB>
__device__ __forceinline__ void gemm64_tile(
    LdsU* L, int tm, int tn,
    const short* __restrict__ A, int lda, const short* __restrict__ W, int ldw,
    void* __restrict__ Cout, int ldc, int Kd,
    const float* __restrict__ bias, const float* __restrict__ extra,
    void* __restrict__ out2, const float* __restrict__ bias2)
{
    const int tid = threadIdx.x, wave = tid >> 6, lane = tid & 63;
    const int m0 = tm * 64, n0 = tn * 64;
    const int wm = wave >> 1, wn = wave & 1;
    const int l15 = lane & 15, kg = lane >> 4;
    const int p = wave * 64 + lane;   // 16B chunk id: row p>>2, slot p&3
    const short* srcA = A + (size_t)(m0 + (p >> 2)) * lda + (p & 3) * 8;
    const short* srcB = W + (size_t)(n0 + (p >> 2)) * ldw + (p & 3) * 8;
    short* ldsA = L->gm.A + (size_t)(wave * 64) * 8;   // wave-uniform base
    short* ldsB = L->gm.B + (size_t)(wave * 64) * 8;

    f32x4 acc[2][2] = {};
    for (int k0 = 0; k0 < Kd; k0 += 32) {
        __syncthreads();
        __builtin_amdgcn_global_load_lds((const glb_u32_t*)(srcA + k0), (lds_u32_t*)ldsA, 16, 0, 0);
        __builtin_amdgcn_global_load_lds((const glb_u32_t*)(srcB + k0), (lds_u32_t*)ldsB, 16, 0, 0);
        __syncthreads();
        short8 af[2], bfr[2];
#pragma unroll
        for (int mi = 0; mi < 2; mi++)
            af[mi] = *(const short8*)(L->gm.A + (wm * 32 + mi * 16 + l15) * 32 + kg * 8);
#pragma unroll
        for (int ni = 0; ni < 2; ni++)
            bfr[ni] = *(const short8*)(L->gm.B + (wn * 32 + ni * 16 + l15) * 32 + kg * 8);
#pragma unroll
        for (int mi = 0; mi < 2; mi++)
#pragma unroll
            for (int ni = 0; ni < 2; ni++)
                acc[mi][ni] = __builtin_amdgcn_mfma_f32_16x16x32_bf16(af[mi], bfr[ni], acc[mi][ni], 0, 0, 0);
    }

    // C/D frag: col=lane&15, row=(lane>>4)*4+j  [m89]
#pragma unroll
    for (int ni = 0; ni < 2; ni++) {
        const int col = n0 + wn * 32 + ni * 16 + l15;
        float b = 0.f;
        bool isG = false;
        if constexpr (EPI == EPI_SPATIAL1) {
            isG = (col >= 512);
            b = isG ? bias2[col - 512] : bias[col];
        } else if constexpr (EPI == EPI_BIAS_MUL) {
            b = bias[col];
        }
#pragma unroll
        for (int mi = 0; mi < 2; mi++) {
#pragma unroll
            for (int j = 0; j < 4; j++) {
                const int row = m0 + wm * 32 + mi * 16 + kg * 4 + j;
                float v = acc[mi][ni][j];
                if constexpr (EPI == EPI_SPATIAL1) {
                    v += b;
                    if (isG)
                        ((float*)out2)[(size_t)row * 512 + (col - 512)] = sigm(v);
                    else
                        ((short*)Cout)[(size_t)row * 512 + col] = f2b(0.5f * v * (1.f + erff(v * 0.70710678f)));
                    continue;
                }
                if constexpr (EPI == EPI_BIAS_MUL) {
                    v += b;
                    v *= extra[(size_t)row * ldc + col];
                } else if constexpr (EPI == EPI_ADD) {
                    v += extra[(size_t)row * ldc + col];
                }
                if constexpr (OUTB)
                    ((short*)Cout)[(size_t)row * ldc + col] = f2b(v);
                else
                    ((float*)Cout)[(size_t)row * ldc + col] = v;
            }
        }
    }
}

// ---- fp32 dt GEMM tile (K=32): delta = softplus(xdbl[:, :32] @ dtw^T + b)
__device__ __forceinline__ void dt_tile(
    LdsU* L, int tm, int tn,
    const float* __restrict__ A, const float* __restrict__ W,
    float* __restrict__ C, const float* __restrict__ bias)
{
    const int tid = threadIdx.x;
    const int m0 = tm * 64, n0 = tn * 64;
    const int row = tid & 63, kgs = tid >> 6;
    const int tr = tid >> 4, tc = tid & 15;
    float acc[4][4] = {};
    const float* ap = A + (size_t)(m0 + row) * 64 + kgs * 4;
    const float* wp = W + (size_t)(n0 + row) * 32 + kgs * 4;
    for (int k0 = 0; k0 < 32; k0 += 16) {
        const float4 a4 = *(const float4*)(ap + k0);
        const float4 b4 = *(const float4*)(wp + k0);
        __syncthreads();
        L->g32.As[kgs * 4 + 0][row] = a4.x; L->g32.As[kgs * 4 + 1][row] = a4.y;
        L->g32.As[kgs * 4 + 2][row] = a4.z; L->g32.As[kgs * 4 + 3][row] = a4.w;
        L->g32.Bs[kgs * 4 + 0][row] = b4.x; L->g32.Bs[kgs * 4 + 1][row] = b4.y;
        L->g32.Bs[kgs * 4 + 2][row] = b4.z; L->g32.Bs[kgs * 4 + 3][row] = b4.w;
        __syncthreads();
#pragma unroll
        for (int k = 0; k < 16; k++) {
            const float4 av = *(const float4*)&L->g32.As[k][tr * 4];
            const float4 bv = *(const float4*)&L->g32.Bs[k][tc * 4];
#pragma unroll
            for (int i = 0; i < 4; i++) {
                const float a = (&av.x)[i];
                acc[i][0] = fmaf(a, bv.x, acc[i][0]);
                acc[i][1] = fmaf(a, bv.y, acc[i][1]);
                acc[i][2] = fmaf(a, bv.z, acc[i][2]);
                acc[i][3] = fmaf(a, bv.w, acc[i][3]);
            }
        }
    }
#pragma unroll
    for (int i = 0; i < 4; i++) {
        const int mm = m0 + tr * 4 + i;
        const int nn = n0 + tc * 4;
        float4 v = make_float4(acc[i][0], acc[i][1], acc[i][2], acc[i][3]);
        const float4 b = *(const float4*)(bias + nn);
        v.x += b.x; v.y += b.y; v.z += b.z; v.w += b.w;
        v.x = fmaxf(v.x, 0.f) + log1pf(__expf(-fabsf(v.x)));
        v.y = fmaxf(v.y, 0.f) + log1pf(__expf(-fabsf(v.y)));
        v.z = fmaxf(v.z, 0.f) + log1pf(__expf(-fabsf(v.z)));
        v.w = fmaxf(v.w, 0.f) + log1pf(__expf(-fabsf(v.w)));
        *(float4*)(C + (size_t)mm * 1024 + nn) = v;
    }
}

// ---- rmsnorm: 4 rows/block (wave per row), active for blk < 256
template <int OUTB>
__device__ __forceinline__ void rms_rows(const float* __restrict__ in, const float* __restrict__ w,
                                         void* __restrict__ out, int blk)
{
    const int lane = threadIdx.x & 63;
    const int rowId = blk * 4 + (threadIdx.x >> 6);
    const float* ip = in + (size_t)rowId * 512 + lane * 8;
    const float4 v1 = *(const float4*)ip;
    const float4 v2 = *(const float4*)(ip + 4);
    float ss = v1.x * v1.x + v1.y * v1.y + v1.z * v1.z + v1.w * v1.w
             + v2.x * v2.x + v2.y * v2.y + v2.z * v2.z + v2.w * v2.w;
#pragma unroll
    for (int off = 32; off > 0; off >>= 1) ss += __shfl_xor(ss, off, 64);
    const float rs = rsqrtf(ss * (1.f / 512.f) + 1e-5f);
    const float4 w1 = *(const float4*)(w + lane * 8);
    const float4 w2 = *(const float4*)(w + lane * 8 + 4);
    const float o[8] = { v1.x * rs * w1.x, v1.y * rs * w1.y, v1.z * rs * w1.z, v1.w * rs * w1.w,
                         v2.x * rs * w2.x, v2.y * rs * w2.y, v2.z * rs * w2.z, v2.w * rs * w2.w };
    if constexpr (OUTB) {
        short8 pk;
#pragma unroll
        for (int i = 0; i < 8; i++) pk[i] = f2b(o[i]);
        *(short8*)((short*)out + (size_t)rowId * 512 + lane * 8) = pk;
    } else {
        float* op = (float*)out + (size_t)rowId * 512 + lane * 8;
        *(float4*)op       = make_float4(o[0], o[1], o[2], o[3]);
        *(float4*)(op + 4) = make_float4(o[4], o[5], o[6], o[7]);
    }
}

// ---- depthwise causal conv + bias + silu; 8 virtual blocks per real block
__device__ __forceinline__ void conv_phase(const float* __restrict__ xr, const float* __restrict__ cw,
                                           const float* __restrict__ cb, float* __restrict__ xc,
                                           short* __restrict__ xcb, int blk)
{
    const int base = blk * 256 + threadIdx.x;       // d constant across iterations
    const int d = base & (DINNER - 1);
    const float4 w4 = *(const float4*)(cw + d * 4);
    const float bia = cb[d];
#pragma unroll
    for (int it = 0; it < 8; it++) {
        const int idx = it * 131072 + base;
        const int m = idx >> 10;
        const int l = m & (SEQ - 1);
        float acc = bia;
#pragma unroll
        for (int j = 0; j < 4; j++) {
            const int li = l + j - 3;
            if (li >= 0) acc += xr[(size_t)(m + j - 3) * 2048 + d] * (&w4.x)[j];
        }
        const float v = acc * sigm(acc);
        xc[idx] = v;
        xcb[idx] = f2b(v);
    }
}

// ---- selective scan + fused silu(res) gate; active for blk < 64
__device__ __forceinline__ void scan_phase(
    LdsU* L, const float* __restrict__ xc, const float* __restrict__ delta,
    const float* __restrict__ xdbl, const float* __restrict__ Alog,
    const float* __restrict__ Dp, const float* __restrict__ xr, short* __restrict__ yb, int blk)
{
    const int b = blk >> 2;
    const int d = ((blk & 3) << 8) + threadIdx.x;
    for (int i = threadIdx.x; i < SEQ * DFF; i += 256) {
        const int l = i >> 4, n = i & 15;
        L->sc.Bm[l][n] = xdbl[(size_t)(b * SEQ + l) * 64 + DTRANK + n];
        L->sc.Cm[l][n] = xdbl[(size_t)(b * SEQ + l) * 64 + DTRANK + DFF + n];
    }
    __syncthreads();
    float a[16], s[16];
#pragma unroll
    for (int n = 0; n < 16; n++) { a[n] = -__expf(Alog[(size_t)d * 16 + n]); s[n] = 0.f; }
    const float dv = Dp[d];
    for (int l = 0; l < SEQ; l++) {
        const size_t m = (size_t)b * SEQ + l;
        const float dlt = delta[m * DINNER + d];
        const float u = xc[m * DINNER + d];
        const float dbu = dlt * u;
        float acc = 0.f;
#pragma unroll
        for (int n = 0; n < 16; n++) {
            s[n] = __expf(dlt * a[n]) * s[n] + dbu * L->sc.Bm[l][n];
            acc = fmaf(s[n], L->sc.Cm[l][n], acc);
        }
        acc = fmaf(u, dv, acc);
        const float r = xr[m * 2048 + DINNER + d];
        yb[m * DINNER + d] = f2b(acc * (r * sigm(r)));
    }
}

// ---- coeffs + preds for one (b,k) row m
__device__ __forceinline__ void coeffs_phase(
    LdsU* L, const float* __restrict__ outp, const float* __restrict__ inp,
    float* __restrict__ coeffs, float* __restrict__ preds, int m)
{
    const int b = m >> 6;
    const int tid = threadIdx.x, wave = tid >> 6, lane = tid & 63;
    L->co.Us[tid] = *(const float4*)(outp + (size_t)m * 2048 + tid * 4);
    L->co.Vs[tid] = *(const float4*)(outp + (size_t)m * 2048 + 1024 + tid * 4);
    L->co.ins[tid] = inp[(size_t)m * 256 + tid];
    __syncthreads();
    const float4 vq0 = L->co.Vs[lane * 4 + 0], vq1 = L->co.Vs[lane * 4 + 1];
    const float4 vq2 = L->co.Vs[lane * 4 + 2], vq3 = L->co.Vs[lane * 4 + 3];
    float* cbase = coeffs + (size_t)m * 65536 + lane * 4;
#pragma unroll 4
    for (int i = 0; i < 64; i++) {
        const int pp = (wave << 6) + i;
        const float4 up = L->co.Us[pp];
        float4 c;
        c.x = up.x * vq0.x + up.y * vq0.y + up.z * vq0.z + up.w * vq0.w;
        c.y = up.x * vq1.x + up.y * vq1.y + up.z * vq1.z + up.w * vq1.w;
        c.z = up.x * vq2.x + up.y * vq2.y + up.z * vq2.z + up.w * vq2.w;
        c.w = up.x * vq3.x + up.y * vq3.y + up.z * vq3.z + up.w * vq3.w;
        *(float4*)(cbase + (size_t)pp * 256) = c;
    }
    const float iv = L->co.ins[tid];
    const float4 vm = L->co.Vs[tid];
    float4 t = make_float4(vm.x * iv, vm.y * iv, vm.z * iv, vm.w * iv);
#pragma unroll
    for (int off = 32; off > 0; off >>= 1) {
        t.x += __shfl_xor(t.x, off, 64);
        t.y += __shfl_xor(t.y, off, 64);
        t.z += __shfl_xor(t.z, off, 64);
        t.w += __shfl_xor(t.w, off, 64);
    }
    if (lane == 0) L->co.tpart[wave] = t;
    __syncthreads();
    const float4 t0 = L->co.tpart[0], t1 = L->co.tpart[1], t2 = L->co.tpart[2], t3 = L->co.tpart[3];
    const float4 tt = make_float4(t0.x + t1.x + t2.x + t3.x, t0.y + t1.y + t2.y + t3.y,
                                  t0.z + t1.z + t2.z + t3.z, t0.w + t1.w + t2.w + t3.w);
    const float4 up = L->co.Us[tid];
    const float pv = up.x * tt.x + up.y * tt.y + up.z * tt.z + up.w * tt.w;
    atomicAdd(preds + (size_t)b * 256 + tid, pv);
}

// ---- the mega kernel (plain launch; manual grid barrier) ----
__global__ __launch_bounds__(256, 2) void mega_k(P p)
{
    __shared__ LdsU L;
    const int blk = blockIdx.x;   // 0..511
    const int tid = threadIdx.x;
    unsigned* cnt = p.bar;
    unsigned* gen = p.bar + 16;   // separate cachelines

    // phase 0: weight/input bf16 conversion (8192 x 1024-elem chunks) + zero preds
    {
        constexpr int pre[9] = {0, 128, 256, 512, 4608, 4864, 6912, 7936, 8192};
        for (int vb = blk; vb < 8192; vb += 512) {
            int s = 0;
#pragma unroll
            for (int i = 1; i < 8; i++) s += (vb >= pre[i]);
            const float* src; short* dst;
            if      (s == 0) { src = p.lin1_w;     dst = p.wlin1b; }
            else if (s == 1) { src = p.gate_w;     dst = p.wgateb; }
            else if (s == 2) { src = p.lin2_w;     dst = p.wlin2b; }
            else if (s == 3) { src = p.in_proj_w;  dst = p.winpb;  }
            else if (s == 4) { src = p.x_proj_w;   dst = p.wxpb;   }
            else if (s == 5) { src = p.out_proj_w; dst = p.woutpb; }
            else if (s == 6) { src = p.proj_w;     dst = p.wprojb; }
            else             { src = p.inputs;     dst = p.inputsb;}
            const int off = (vb - pre[s]) * 1024 + tid * 4;
            const float4 v = *(const float4*)(src + off);
            union { short sh[4]; uint2 u; } pk;
            pk.sh[0] = f2b(v.x); pk.sh[1] = f2b(v.y); pk.sh[2] = f2b(v.z); pk.sh[3] = f2b(v.w);
            *(uint2*)(dst + off) = pk.u;
        }
        for (int i = blk * 256 + tid; i < 4096; i += 512 * 256) p.preds[i] = 0.f;
    }
    gbar(cnt, gen);

    // spatial: lin1+gate fused (N=1024 concat weights), 256 tiles
    if (blk < 256)
        gemm64_tile<EPI_SPATIAL1, 1>(&L, blk >> 4, blk & 15, p.inputsb, 256, p.wlin1b, 256,
                                     p.h1b, 512, 256, p.lin1_b, nullptr, p.g, p.gate_b);
    gbar(cnt, gen);
    if (blk < 128)
        gemm64_tile<EPI_BIAS_MUL, 0>(&L, blk >> 3, blk & 7, p.h1b, 512, p.wlin2b, 512,
                                     p.xc, 512, 512, p.lin2_b, p.g, nullptr, nullptr);
    gbar(cnt, gen);
    if (blk < 256) rms_rows<0>(p.xc, p.sp_norm_w, p.h, blk);
    gbar(cnt, gen);

    for (int l = 0; l < 4; l++) {
        if (blk < 256) rms_rows<1>(p.h, p.blk_norm_w + l * 512, p.hnb, blk);
        gbar(cnt, gen);
        // in_proj: 1024x2048, K=512 -> 512 tiles (full grid)
        gemm64_tile<EPI_NONE, 0>(&L, blk >> 5, blk & 31, p.hnb, 512, p.winpb + (size_t)l * 1048576, 512,
                                 p.xr, 2048, 512, nullptr, nullptr, nullptr, nullptr);
        gbar(cnt, gen);
        conv_phase(p.xr, p.conv_w + (size_t)l * 4096, p.conv_b + l * 1024, p.xc, p.xcb, blk);
        gbar(cnt, gen);
        if (blk < 16)
            gemm64_tile<EPI_NONE, 0>(&L, blk, 0, p.xcb, 1024, p.wxpb + (size_t)l * 65536, 1024,
                                     p.xdbl, 64, 1024, nullptr, nullptr, nullptr, nullptr);
        gbar(cnt, gen);
        if (blk < 256)
            dt_tile(&L, blk >> 4, blk & 15, p.xdbl, p.dt_proj_w + (size_t)l * 32768,
                    p.delta, p.dt_proj_b + l * 1024);
        gbar(cnt, gen);
        if (blk < 64)
            scan_phase(&L, p.xc, p.delta, p.xdbl, p.A_log + (size_t)l * 16384,
                       p.Dvec + l * 1024, p.xr, p.yb, blk);
        gbar(cnt, gen);
        if (blk < 128)
            gemm64_tile<EPI_ADD, 0>(&L, blk >> 3, blk & 7, p.yb, 1024, p.woutpb + (size_t)l * 524288, 1024,
                                    p.h, 512, 1024, nullptr, p.h, nullptr, nullptr);
        gbar(cnt, gen);
    }

    if (blk < 256) rms_rows<1>(p.h, p.post_norm_w, p.hnb, blk);
    gbar(cnt, gen);
    // final proj: 1024x2048, K=512 -> 512 tiles (full grid)
    gemm64_tile<EPI_NONE, 0>(&L, blk >> 5, blk & 31, p.hnb, 512, p.wprojb, 512,
                             p.xr, 2048, 512, nullptr, nullptr, nullptr, nullptr);
    gbar(cnt, gen);

    // coeffs + preds: 1024 m-rows over 512 blocks (2 each)
    for (int mm = blk; mm < 1024; mm += 512) {
        __syncthreads();   // protect LDS reuse between iterations
        coeffs_phase(&L, p.xr, p.inputs, p.coeffs, p.preds, mm);
    }
}

} // namespace

extern "C" void kernel_launch(void* const* d_in, const int* in_sizes, int n_in,
                              void* d_out, int out_size, void* d_ws, size_t ws_size,
                              hipStream_t stream)
{
    float* ws = (float*)d_ws;
    short* bfb = (short*)(ws + 4784128);

    P p;
    p.inputs      = (const float*)d_in[0];
    p.lin1_w      = (const float*)d_in[1];
    p.lin1_b      = (const float*)d_in[2];
    p.lin2_w      = (const float*)d_in[3];
    p.lin2_b      = (const float*)d_in[4];
    p.gate_w      = (const float*)d_in[5];
    p.gate_b      = (const float*)d_in[6];
    p.sp_norm_w   = (const float*)d_in[7];
    p.in_proj_w   = (const float*)d_in[8];
    p.conv_w      = (const float*)d_in[9];
    p.conv_b      = (const float*)d_in[10];
    p.x_proj_w    = (const float*)d_in[11];
    p.dt_proj_w   = (const float*)d_in[12];
    p.dt_proj_b   = (const float*)d_in[13];
    p.A_log       = (const float*)d_in[14];
    p.Dvec        = (const float*)d_in[15];
    p.out_proj_w  = (const float*)d_in[16];
    p.blk_norm_w  = (const float*)d_in[17];
    p.post_norm_w = (const float*)d_in[18];
    p.proj_w      = (const float*)d_in[19];

    p.h     = ws;                  // 1024 x 512
    p.xr    = ws + 524288;         // 1024 x 2048
    p.xc    = ws + 2621440;        // 1024 x 1024 (spatial hn alias)
    p.delta = ws + 3670016;        // 1024 x 1024 (spatial g alias)
    p.g     = p.delta;
    p.xdbl  = ws + 4718592;        // 1024 x 64
    p.inputsb = bfb;               // 1024 x 256
    p.hnb     = bfb + 262144;      // 1024 x 512
    p.xcb     = bfb + 786432;      // 1024 x 1024
    p.yb      = bfb + 1835008;     // 1024 x 1024 (spatial h1b alias)
    p.h1b     = p.yb;
    p.wlin1b  = bfb + 2883584;     // 512 x 256   (wgateb adjacent -> concat N=1024)
    p.wgateb  = bfb + 3014656;     // 512 x 256
    p.wlin2b  = bfb + 3145728;     // 512 x 512
    p.winpb   = bfb + 3407872;     // 4 x 2048 x 512
    p.wxpb    = bfb + 7602176;     // 4 x 64 x 1024
    p.woutpb  = bfb + 7864320;     // 4 x 512 x 1024
    p.wprojb  = bfb + 9961472;     // 2048 x 512
    p.bar     = (unsigned*)(bfb + 11010048);   // 2 cachelines of barrier state
    p.preds   = (float*)d_out;
    p.coeffs  = (float*)d_out + 4096;

    hipMemsetAsync(p.bar, 0, 128, stream);
    mega_k<<<dim3(NBLK), dim3(256), 0, stream>>>(p);
}

// Round 5
// 819.445 us; speedup vs baseline: 2.7489x; 2.7489x over previous
//
#include <hip/hip_runtime.h>
#include <hip/hip_bf16.h>
#include <math.h>

namespace {

constexpr int SEQ    = 64;
constexpr int DINNER = 1024;
constexpr int DFF    = 16;
constexpr int DTRANK = 32;

typedef __attribute__((ext_vector_type(8))) short short8;
typedef __attribute__((ext_vector_type(4))) float f32x4;
typedef __attribute__((address_space(3))) unsigned int lds_u32_t;
typedef __attribute__((address_space(1))) unsigned int glb_u32_t;

__device__ __forceinline__ float sigm(float x) { return 1.f / (1.f + __expf(-x)); }
__device__ __forceinline__ short f2b(float v) {
    __hip_bfloat16 h = __float2bfloat16(v);
    return *(short*)&h;
}
__device__ __forceinline__ float softp(float v) {
    return fmaxf(v, 0.f) + log1pf(__expf(-fabsf(v)));
}

// ================= bf16 MFMA GEMM core: BM=128 x BN, BK=32, 4 waves (2x2) ==========
// acc[mi][ni]; A,W row-major bf16 (W is N x K). Verified structure from R2.
template <int BN>
__device__ __forceinline__ void gemm_core(
    f32x4 (&acc)[4][BN / 32],
    const short* __restrict__ A, int lda,
    const short* __restrict__ W, int ldw,
    int Kd, short* As, short* Bs, int m0, int n0)
{
    constexpr int NFR = BN / 32;
    const int tid = threadIdx.x, wave = tid >> 6, lane = tid & 63;
    const int wm = wave >> 1, wn = wave & 1;
    const int l15 = lane & 15, kg = lane >> 4;

    const int pA0 = wave * 128 + lane, pA1 = pA0 + 64;
    const short* srcA0 = A + (size_t)(m0 + (pA0 >> 2)) * lda + (pA0 & 3) * 8;
    const short* srcA1 = A + (size_t)(m0 + (pA1 >> 2)) * lda + (pA1 & 3) * 8;
    short* ldsA0 = As + (size_t)(wave * 128) * 8;
    short* ldsA1 = As + (size_t)(wave * 128 + 64) * 8;

    const short* srcB0; const short* srcB1 = nullptr;
    short* ldsB0; short* ldsB1 = nullptr;
    if constexpr (BN == 128) {
        const int pB0 = wave * 128 + lane, pB1 = pB0 + 64;
        srcB0 = W + (size_t)(n0 + (pB0 >> 2)) * ldw + (pB0 & 3) * 8;
        srcB1 = W + (size_t)(n0 + (pB1 >> 2)) * ldw + (pB1 & 3) * 8;
        ldsB0 = Bs + (size_t)(wave * 128) * 8;
        ldsB1 = Bs + (size_t)(wave * 128 + 64) * 8;
    } else {
        const int pB0 = wave * 64 + lane;
        srcB0 = W + (size_t)(n0 + (pB0 >> 2)) * ldw + (pB0 & 3) * 8;
        ldsB0 = Bs + (size_t)(wave * 64) * 8;
    }

    for (int k0 = 0; k0 < Kd; k0 += 32) {
        __syncthreads();
        __builtin_amdgcn_global_load_lds((const glb_u32_t*)(srcA0 + k0), (lds_u32_t*)ldsA0, 16, 0, 0);
        __builtin_amdgcn_global_load_lds((const glb_u32_t*)(srcA1 + k0), (lds_u32_t*)ldsA1, 16, 0, 0);
        __builtin_amdgcn_global_load_lds((const glb_u32_t*)(srcB0 + k0), (lds_u32_t*)ldsB0, 16, 0, 0);
        if constexpr (BN == 128)
            __builtin_amdgcn_global_load_lds((const glb_u32_t*)(srcB1 + k0), (lds_u32_t*)ldsB1, 16, 0, 0);
        __syncthreads();

        short8 af[4], bfr[NFR];
#pragma unroll
        for (int mi = 0; mi < 4; mi++)
            af[mi] = *(const short8*)(As + (wm * 64 + mi * 16 + l15) * 32 + kg * 8);
#pragma unroll
        for (int ni = 0; ni < NFR; ni++)
            bfr[ni] = *(const short8*)(Bs + (wn * (BN / 2) + ni * 16 + l15) * 32 + kg * 8);
#pragma unroll
        for (int mi = 0; mi < 4; mi++)
#pragma unroll
            for (int ni = 0; ni < NFR; ni++)
                acc[mi][ni] = __builtin_amdgcn_mfma_f32_16x16x32_bf16(af[mi], bfr[ni], acc[mi][ni], 0, 0, 0);
    }
}
// C/D frag mapping [m89]: col = n0 + wn*(BN/2) + ni*16 + (lane&15);
//                         row = m0 + wm*64 + mi*16 + (lane>>4)*4 + j

// ================= prep: conversions (+gamma fold), W_delta, zeroing =================
__global__ __launch_bounds__(256) void prep_k(
    const float* __restrict__ lin1_w, const float* __restrict__ gate_w,
    const float* __restrict__ lin2_w, const float* __restrict__ in_proj_w,
    const float* __restrict__ out_proj_w, const float* __restrict__ proj_w,
    const float* __restrict__ x_proj_w, const float* __restrict__ dt_proj_w,
    const float* __restrict__ inputs, const float* __restrict__ blk_norm_w,
    const float* __restrict__ post_norm_w,
    short* __restrict__ wlin1gb, short* __restrict__ wlin2b, short* __restrict__ winpb,
    short* __restrict__ woutpb, short* __restrict__ wprojb, short* __restrict__ wxpdb,
    short* __restrict__ inputsb, float* __restrict__ preds, float* __restrict__ ss)
{
    const int blk = blockIdx.x, tid = threadIdx.x;
    if (blk < 1024) {
        // W_delta = dt_w(1024x32) @ xp_w[:32](32x1024), per layer; wave per n-row
        const int wave = tid >> 6, lane = tid & 63;
        const int nrow = blk * 4 + wave;          // 0..4095
        const int l = nrow >> 10, n = nrow & 1023;
        const float* dtw = dt_proj_w + (size_t)l * 32768 + n * 32;
        const float* xpw = x_proj_w + (size_t)l * 65536;
        float4 acc[4] = {};
        for (int r = 0; r < 32; r++) {
            const float s = dtw[r];
#pragma unroll
            for (int rep = 0; rep < 4; rep++) {
                const float4 xv = *(const float4*)(xpw + r * 1024 + rep * 256 + lane * 4);
                acc[rep].x = fmaf(s, xv.x, acc[rep].x);
                acc[rep].y = fmaf(s, xv.y, acc[rep].y);
                acc[rep].z = fmaf(s, xv.z, acc[rep].z);
                acc[rep].w = fmaf(s, xv.w, acc[rep].w);
            }
        }
        short* dst = wxpdb + (size_t)l * 1114112 + (size_t)(64 + n) * 1024;
#pragma unroll
        for (int rep = 0; rep < 4; rep++) {
            union { short sh[4]; uint2 u; } pk;
            pk.sh[0] = f2b(acc[rep].x); pk.sh[1] = f2b(acc[rep].y);
            pk.sh[2] = f2b(acc[rep].z); pk.sh[3] = f2b(acc[rep].w);
            *(uint2*)(dst + rep * 256 + lane * 4) = pk.u;
        }
    } else if (blk < 1088) {
        // copy xp_w rows 0..63 (bf16) into wxpdb rows 0..63
#pragma unroll
        for (int rep = 0; rep < 4; rep++) {
            const int e = (blk - 1024) * 4096 + rep * 1024 + tid * 4;  // < 262144
            const int l = e >> 16, rowk = e & 65535;
            const float4 v = *(const float4*)(x_proj_w + (size_t)l * 65536 + rowk);
            union { short sh[4]; uint2 u; } pk;
            pk.sh[0] = f2b(v.x); pk.sh[1] = f2b(v.y); pk.sh[2] = f2b(v.z); pk.sh[3] = f2b(v.w);
            *(uint2*)(wxpdb + (size_t)l * 1114112 + rowk) = pk.u;
        }
    } else if (blk < 2048) {
        // plain conversions with optional gamma folding; 7936 chunks of 1024 elems
        constexpr int pre[8] = {0, 128, 256, 512, 4608, 6656, 7680, 7936};
        for (int vb = blk - 1088; vb < 7936; vb += 960) {
            int s = 0;
#pragma unroll
            for (int i = 1; i < 7; i++) s += (vb >= pre[i]);
            const int e = (vb - pre[s]) * 1024 + tid * 4;
            const float* src; short* dst;
            bool hasG = false; const float* gp = nullptr;
            if      (s == 0) { src = lin1_w + e;     dst = wlin1gb + e; }
            else if (s == 1) { src = gate_w + e;     dst = wlin1gb + 131072 + e; }
            else if (s == 2) { src = lin2_w + e;     dst = wlin2b + e; }
            else if (s == 3) { src = in_proj_w + e;  dst = winpb + e;
                               hasG = true; gp = blk_norm_w + (e >> 20) * 512 + (e & 511); }
            else if (s == 4) { src = out_proj_w + e; dst = woutpb + e; }
            else if (s == 5) { src = proj_w + e;     dst = wprojb + e;
                               hasG = true; gp = post_norm_w + (e & 511); }
            else             { src = inputs + e;     dst = inputsb + e; }
            float4 v = *(const float4*)src;
            if (hasG) {
                const float4 gv = *(const float4*)gp;
                v.x *= gv.x; v.y *= gv.y; v.z *= gv.z; v.w *= gv.w;
            }
            union { short sh[4]; uint2 u; } pk;
            pk.sh[0] = f2b(v.x); pk.sh[1] = f2b(v.y); pk.sh[2] = f2b(v.z); pk.sh[3] = f2b(v.w);
            *(uint2*)dst = pk.u;
        }
    } else {
        const int i = (blk - 2048) * 256 + tid;   // < 8192
        if (i < 4096) preds[i] = 0.f;
        else ss[1024 + (i - 4096)] = 0.f;          // zero ss slots 1..4
    }
}

// ================= spatial: lin1|gate merged (N=1024) =================
__global__ __launch_bounds__(256) void lin1gate_k(
    const short* __restrict__ A, const short* __restrict__ W,
    const float* __restrict__ b1, const float* __restrict__ b2,
    short* __restrict__ h1b, float* __restrict__ g)
{
    __shared__ short As[128 * 32];
    __shared__ short Bs[128 * 32];
    f32x4 acc[4][4] = {};
    const int m0 = blockIdx.y * 128, n0 = blockIdx.x * 128;
    gemm_core<128>(acc, A, 256, W, 256, 256, As, Bs, m0, n0);
    const int lane = threadIdx.x & 63, wave = threadIdx.x >> 6;
    const int wm = wave >> 1, wn = wave & 1, l15 = lane & 15, kg = lane >> 4;
#pragma unroll
    for (int ni = 0; ni < 4; ni++) {
        const int col = n0 + wn * 64 + ni * 16 + l15;
        const bool isG = col >= 512;
        const float b = isG ? b2[col - 512] : b1[col];
#pragma unroll
        for (int mi = 0; mi < 4; mi++)
#pragma unroll
            for (int j = 0; j < 4; j++) {
                const int row = m0 + wm * 64 + mi * 16 + kg * 4 + j;
                const float v = acc[mi][ni][j] + b;
                if (isG) g[(size_t)row * 512 + (col - 512)] = sigm(v);
                else     h1b[(size_t)row * 512 + col] = f2b(0.5f * v * (1.f + erff(v * 0.70710678f)));
            }
    }
}

// ================= lin2: x = (h1 @ W^T + b) * g =================
__global__ __launch_bounds__(256) void lin2_k(
    const short* __restrict__ A, const short* __restrict__ W,
    const float* __restrict__ bias, const float* __restrict__ g, float* __restrict__ x)
{
    __shared__ short As[128 * 32];
    __shared__ short Bs[128 * 32];
    f32x4 acc[4][4] = {};
    const int m0 = blockIdx.y * 128, n0 = blockIdx.x * 128;
    gemm_core<128>(acc, A, 512, W, 512, 512, As, Bs, m0, n0);
    const int lane = threadIdx.x & 63, wave = threadIdx.x >> 6;
    const int wm = wave >> 1, wn = wave & 1, l15 = lane & 15, kg = lane >> 4;
#pragma unroll
    for (int ni = 0; ni < 4; ni++) {
        const int col = n0 + wn * 64 + ni * 16 + l15;
        const float b = bias[col];
#pragma unroll
        for (int mi = 0; mi < 4; mi++)
#pragma unroll
            for (int j = 0; j < 4; j++) {
                const int row = m0 + wm * 64 + mi * 16 + kg * 4 + j;
                x[(size_t)row * 512 + col] = (acc[mi][ni][j] + b) * g[(size_t)row * 512 + col];
            }
    }
}

// ================= spatial rmsnorm: h fp32 + hb bf16 + ss[0] =================
__global__ __launch_bounds__(256) void rms_sp_k(
    const float* __restrict__ x, const float* __restrict__ w,
    float* __restrict__ h, short* __restrict__ hb, float* __restrict__ ss0)
{
    const int lane = threadIdx.x & 63;
    const int rowId = blockIdx.x * 4 + (threadIdx.x >> 6);
    const float* ip = x + (size_t)rowId * 512 + lane * 8;
    const float4 v1 = *(const float4*)ip;
    const float4 v2 = *(const float4*)(ip + 4);
    float sq = v1.x * v1.x + v1.y * v1.y + v1.z * v1.z + v1.w * v1.w
             + v2.x * v2.x + v2.y * v2.y + v2.z * v2.z + v2.w * v2.w;
#pragma unroll
    for (int off = 32; off > 0; off >>= 1) sq += __shfl_xor(sq, off, 64);
    const float rs = rsqrtf(sq * (1.f / 512.f) + 1e-5f);
    const float4 w1 = *(const float4*)(w + lane * 8);
    const float4 w2 = *(const float4*)(w + lane * 8 + 4);
    const float o[8] = { v1.x * rs * w1.x, v1.y * rs * w1.y, v1.z * rs * w1.z, v1.w * rs * w1.w,
                         v2.x * rs * w2.x, v2.y * rs * w2.y, v2.z * rs * w2.z, v2.w * rs * w2.w };
    float* op = h + (size_t)rowId * 512 + lane * 8;
    *(float4*)op       = make_float4(o[0], o[1], o[2], o[3]);
    *(float4*)(op + 4) = make_float4(o[4], o[5], o[6], o[7]);
    short8 pk;
#pragma unroll
    for (int i = 0; i < 8; i++) pk[i] = f2b(o[i]);
    *(short8*)(hb + (size_t)rowId * 512 + lane * 8) = pk;
    float s2 = 0.f;
#pragma unroll
    for (int i = 0; i < 8; i++) s2 = fmaf(o[i], o[i], s2);
#pragma unroll
    for (int off = 32; off > 0; off >>= 1) s2 += __shfl_xor(s2, off, 64);
    if (lane == 0) ss0[rowId] = s2;
}

// ================= in_proj: xr = r[row] * (hb @ (W.gamma)^T) =================
__global__ __launch_bounds__(256) void inproj_k(
    const short* __restrict__ A, const short* __restrict__ W,
    const float* __restrict__ ss_in, float* __restrict__ xr)
{
    __shared__ short As[128 * 32];
    __shared__ short Bs[128 * 32];
    f32x4 acc[4][4] = {};
    const int m0 = blockIdx.y * 128, n0 = blockIdx.x * 128;
    gemm_core<128>(acc, A, 512, W, 512, 512, As, Bs, m0, n0);
    const int lane = threadIdx.x & 63, wave = threadIdx.x >> 6;
    const int wm = wave >> 1, wn = wave & 1, l15 = lane & 15, kg = lane >> 4;
#pragma unroll
    for (int mi = 0; mi < 4; mi++)
#pragma unroll
        for (int j = 0; j < 4; j++) {
            const int row = m0 + wm * 64 + mi * 16 + kg * 4 + j;
            const float r = rsqrtf(ss_in[row] * (1.f / 512.f) + 1e-5f);
#pragma unroll
            for (int ni = 0; ni < 4; ni++) {
                const int col = n0 + wn * 64 + ni * 16 + l15;
                xr[(size_t)row * 2048 + col] = acc[mi][ni][j] * r;
            }
        }
}

// ================= conv + silu =================
__global__ __launch_bounds__(256) void conv_k(
    const float* __restrict__ xr, const float* __restrict__ cw,
    const float* __restrict__ cb, float* __restrict__ xc, short* __restrict__ xcb)
{
    const int idx = blockIdx.x * 256 + threadIdx.x;
    const int d = idx & (DINNER - 1);
    const int m = idx >> 10;
    const int l = m & (SEQ - 1);
    const float4 w4 = *(const float4*)(cw + d * 4);
    float acc = cb[d];
#pragma unroll
    for (int j = 0; j < 4; j++) {
        const int li = l + j - 3;
        if (li >= 0) acc += xr[(size_t)(m + j - 3) * 2048 + d] * (&w4.x)[j];
    }
    const float v = acc * sigm(acc);
    xc[idx] = v;
    xcb[idx] = f2b(v);
}

// ================= xpd: [xdbl | delta] = xcb @ [xpw; W_delta]^T (N=1088) =================
__global__ __launch_bounds__(256) void xpd_k(
    const short* __restrict__ A, const short* __restrict__ W,
    const float* __restrict__ dtb, float* __restrict__ xdbl, float* __restrict__ delta)
{
    __shared__ short As[128 * 32];
    __shared__ short Bs[64 * 32];
    f32x4 acc[4][2] = {};
    const int m0 = blockIdx.y * 128, n0 = blockIdx.x * 64;
    gemm_core<64>(acc, A, 1024, W, 1024, 1024, As, Bs, m0, n0);
    const int lane = threadIdx.x & 63, wave = threadIdx.x >> 6;
    const int wm = wave >> 1, wn = wave & 1, l15 = lane & 15, kg = lane >> 4;
#pragma unroll
    for (int ni = 0; ni < 2; ni++) {
        const int col = n0 + wn * 32 + ni * 16 + l15;
#pragma unroll
        for (int mi = 0; mi < 4; mi++)
#pragma unroll
            for (int j = 0; j < 4; j++) {
                const int row = m0 + wm * 64 + mi * 16 + kg * 4 + j;
                const float v = acc[mi][ni][j];
                if (col < 64) xdbl[(size_t)row * 64 + col] = v;
                else          delta[(size_t)row * 1024 + (col - 64)] = softp(v + dtb[col - 64]);
            }
    }
}

// ================= scan + silu(res) gate =================
__global__ __launch_bounds__(256) void scan_k(
    const float* __restrict__ xc, const float* __restrict__ delta,
    const float* __restrict__ xdbl, const float* __restrict__ Alog,
    const float* __restrict__ Dp, const float* __restrict__ xr, short* __restrict__ yb)
{
    const int b = blockIdx.x >> 2;
    const int d = ((blockIdx.x & 3) << 8) + threadIdx.x;
    __shared__ float Bsh[SEQ][DFF];
    __shared__ float Csh[SEQ][DFF];
    for (int i = threadIdx.x; i < SEQ * DFF; i += 256) {
        const int l = i >> 4, n = i & 15;
        Bsh[l][n] = xdbl[(size_t)(b * SEQ + l) * 64 + DTRANK + n];
        Csh[l][n] = xdbl[(size_t)(b * SEQ + l) * 64 + DTRANK + DFF + n];
    }
    __syncthreads();
    float a[16], s[16];
#pragma unroll
    for (int n = 0; n < 16; n++) { a[n] = -__expf(Alog[(size_t)d * 16 + n]); s[n] = 0.f; }
    const float dv = Dp[d];
    for (int l = 0; l < SEQ; l++) {
        const size_t m = (size_t)b * SEQ + l;
        const float dlt = delta[m * DINNER + d];
        const float u = xc[m * DINNER + d];
        const float dbu = dlt * u;
        float acc = 0.f;
#pragma unroll
        for (int n = 0; n < 16; n++) {
            s[n] = __expf(dlt * a[n]) * s[n] + dbu * Bsh[l][n];
            acc = fmaf(s[n], Csh[l][n], acc);
        }
        acc = fmaf(u, dv, acc);
        const float r = xr[m * 2048 + DINNER + d];
        yb[m * DINNER + d] = f2b(acc * (r * sigm(r)));
    }
}

// ================= out_proj: h += yb @ W^T; writes h fp32 + hb bf16 + ss_out =================
__global__ __launch_bounds__(256) void outproj_k(
    const short* __restrict__ A, const short* __restrict__ W,
    float* __restrict__ h, short* __restrict__ hb, float* __restrict__ ss_out)
{
    __shared__ short As[128 * 32];
    __shared__ short Bs[128 * 32];
    f32x4 acc[4][4] = {};
    const int m0 = blockIdx.y * 128, n0 = blockIdx.x * 128;
    gemm_core<128>(acc, A, 1024, W, 1024, 1024, As, Bs, m0, n0);
    const int lane = threadIdx.x & 63, wave = threadIdx.x >> 6;
    const int wm = wave >> 1, wn = wave & 1, l15 = lane & 15, kg = lane >> 4;
    float vsq[4][4] = {};
#pragma unroll
    for (int ni = 0; ni < 4; ni++) {
        const int col = n0 + wn * 64 + ni * 16 + l15;
#pragma unroll
        for (int mi = 0; mi < 4; mi++)
#pragma unroll
            for (int j = 0; j < 4; j++) {
                const int row = m0 + wm * 64 + mi * 16 + kg * 4 + j;
                const float v = acc[mi][ni][j] + h[(size_t)row * 512 + col];
                h[(size_t)row * 512 + col] = v;
                hb[(size_t)row * 512 + col] = f2b(v);
                vsq[mi][j] = fmaf(v, v, vsq[mi][j]);
            }
    }
#pragma unroll
    for (int mi = 0; mi < 4; mi++)
#pragma unroll
        for (int j = 0; j < 4; j++) {
            float t = vsq[mi][j];
            t += __shfl_xor(t, 1, 64);
            t += __shfl_xor(t, 2, 64);
            t += __shfl_xor(t, 4, 64);
            t += __shfl_xor(t, 8, 64);
            if (l15 == 0) {
                const int row = m0 + wm * 64 + mi * 16 + kg * 4 + j;
                atomicAdd(ss_out + row, t);
            }
        }
}

// ================= final proj: xr = r[row] * (hb @ (W.gamma)^T) =================
__global__ __launch_bounds__(256) void projf_k(
    const short* __restrict__ A, const short* __restrict__ W,
    const float* __restrict__ ss_in, float* __restrict__ xr)
{
    __shared__ short As[128 * 32];
    __shared__ short Bs[128 * 32];
    f32x4 acc[4][4] = {};
    const int m0 = blockIdx.y * 128, n0 = blockIdx.x * 128;
    gemm_core<128>(acc, A, 512, W, 512, 512, As, Bs, m0, n0);
    const int lane = threadIdx.x & 63, wave = threadIdx.x >> 6;
    const int wm = wave >> 1, wn = wave & 1, l15 = lane & 15, kg = lane >> 4;
#pragma unroll
    for (int mi = 0; mi < 4; mi++)
#pragma unroll
        for (int j = 0; j < 4; j++) {
            const int row = m0 + wm * 64 + mi * 16 + kg * 4 + j;
            const float r = rsqrtf(ss_in[row] * (1.f / 512.f) + 1e-5f);
#pragma unroll
            for (int ni = 0; ni < 4; ni++) {
                const int col = n0 + wn * 64 + ni * 16 + l15;
                xr[(size_t)row * 2048 + col] = acc[mi][ni][j] * r;
            }
        }
}

// ================= coeffs + preds =================
__global__ __launch_bounds__(256) void coeffs_k(
    const float* __restrict__ outp, const float* __restrict__ inp,
    float* __restrict__ coeffs, float* __restrict__ preds)
{
    const int m = blockIdx.x;
    const int b = m >> 6;
    const int tid = threadIdx.x, wave = tid >> 6, lane = tid & 63;
    __shared__ float4 Us[256], Vs[256];
    __shared__ float ins[256];
    __shared__ float4 tpart[4];
    Us[tid] = *(const float4*)(outp + (size_t)m * 2048 + tid * 4);
    Vs[tid] = *(const float4*)(outp + (size_t)m * 2048 + 1024 + tid * 4);
    ins[tid] = inp[(size_t)m * 256 + tid];
    __syncthreads();
    const float4 vq0 = Vs[lane * 4 + 0], vq1 = Vs[lane * 4 + 1];
    const float4 vq2 = Vs[lane * 4 + 2], vq3 = Vs[lane * 4 + 3];
    float* cbase = coeffs + (size_t)m * 65536 + lane * 4;
#pragma unroll 4
    for (int i = 0; i < 64; i++) {
        const int pp = (wave << 6) + i;
        const float4 up = Us[pp];
        float4 c;
        c.x = up.x * vq0.x + up.y * vq0.y + up.z * vq0.z + up.w * vq0.w;
        c.y = up.x * vq1.x + up.y * vq1.y + up.z * vq1.z + up.w * vq1.w;
        c.z = up.x * vq2.x + up.y * vq2.y + up.z * vq2.z + up.w * vq2.w;
        c.w = up.x * vq3.x + up.y * vq3.y + up.z * vq3.z + up.w * vq3.w;
        *(float4*)(cbase + (size_t)pp * 256) = c;
    }
    const float iv = ins[tid];
    const float4 vm = Vs[tid];
    float4 t = make_float4(vm.x * iv, vm.y * iv, vm.z * iv, vm.w * iv);
#pragma unroll
    for (int off = 32; off > 0; off >>= 1) {
        t.x += __shfl_xor(t.x, off, 64);
        t.y += __shfl_xor(t.y, off, 64);
        t.z += __shfl_xor(t.z, off, 64);
        t.w += __shfl_xor(t.w, off, 64);
    }
    if (lane == 0) tpart[wave] = t;
    __syncthreads();
    const float4 t0 = tpart[0], t1 = tpart[1], t2 = tpart[2], t3 = tpart[3];
    const float4 tt = make_float4(t0.x + t1.x + t2.x + t3.x, t0.y + t1.y + t2.y + t3.y,
                                  t0.z + t1.z + t2.z + t3.z, t0.w + t1.w + t2.w + t3.w);
    const float4 up = Us[tid];
    const float pv = up.x * tt.x + up.y * tt.y + up.z * tt.z + up.w * tt.w;
    atomicAdd(preds + (size_t)b * 256 + tid, pv);
}

} // namespace

extern "C" void kernel_launch(void* const* d_in, const int* in_sizes, int n_in,
                              void* d_out, int out_size, void* d_ws, size_t ws_size,
                              hipStream_t stream)
{
    const float* inputs     = (const float*)d_in[0];
    const float* lin1_w     = (const float*)d_in[1];
    const float* lin1_b     = (const float*)d_in[2];
    const float* lin2_w     = (const float*)d_in[3];
    const float* lin2_b     = (const float*)d_in[4];
    const float* gate_w     = (const float*)d_in[5];
    const float* gate_b     = (const float*)d_in[6];
    const float* sp_norm_w  = (const float*)d_in[7];
    const float* in_proj_w  = (const float*)d_in[8];
    const float* conv_w     = (const float*)d_in[9];
    const float* conv_b     = (const float*)d_in[10];
    const float* x_proj_w   = (const float*)d_in[11];
    const float* dt_proj_w  = (const float*)d_in[12];
    const float* dt_proj_b  = (const float*)d_in[13];
    const float* A_log      = (const float*)d_in[14];
    const float* Dvec       = (const float*)d_in[15];
    const float* out_proj_w = (const float*)d_in[16];
    const float* blk_norm_w = (const float*)d_in[17];
    const float* post_norm_w= (const float*)d_in[18];
    const float* proj_w     = (const float*)d_in[19];

    float* ws = (float*)d_ws;
    // fp32 region
    float* h     = ws;                 // 1024 x 512
    float* xr    = ws + 524288;        // 1024 x 2048
    float* x     = ws + 2621440;       // 1024 x 512 (lin2 out)
    float* g     = ws + 3145728;       // 1024 x 512
    float* delta = ws + 3670016;       // 1024 x 1024
    float* xc    = ws + 4718592;       // 1024 x 1024
    float* xdbl  = ws + 5767168;       // 1024 x 64
    float* ss    = ws + 5832704;       // 5 x 1024 sumsq slots
    // bf16 region
    short* bfb     = (short*)(ws + 5840896);
    short* inputsb = bfb;               // 1024 x 256
    short* h1b     = bfb + 262144;      // 1024 x 512
    short* hb      = bfb + 786432;      // 1024 x 512
    short* xcb     = bfb + 1310720;     // 1024 x 1024
    short* yb      = bfb + 2359296;     // 1024 x 1024
    short* wlin1gb = bfb + 3407872;     // 1024 x 256 (lin1 rows 0..511, gate rows 512..1023)
    short* wlin2b  = bfb + 3670016;     // 512 x 512
    short* winpb   = bfb + 3932160;     // 4 x 2048 x 512 (gamma-folded)
    short* woutpb  = bfb + 8126464;     // 4 x 512 x 1024
    short* wprojb  = bfb + 10223616;    // 2048 x 512 (gamma-folded)
    short* wxpdb   = bfb + 11272192;    // 4 x 1088 x 1024 ([xpw; W_delta])
    float* preds  = (float*)d_out;
    float* coeffs = (float*)d_out + 4096;

    const dim3 blk(256);

    prep_k<<<dim3(2080), blk, 0, stream>>>(
        lin1_w, gate_w, lin2_w, in_proj_w, out_proj_w, proj_w, x_proj_w, dt_proj_w,
        inputs, blk_norm_w, post_norm_w,
        wlin1gb, wlin2b, winpb, woutpb, wprojb, wxpdb, inputsb, preds, ss);

    lin1gate_k<<<dim3(8, 8), blk, 0, stream>>>(inputsb, wlin1gb, lin1_b, gate_b, h1b, g);
    lin2_k<<<dim3(4, 8), blk, 0, stream>>>(h1b, wlin2b, lin2_b, g, x);
    rms_sp_k<<<dim3(256), blk, 0, stream>>>(x, sp_norm_w, h, hb, ss);

    for (int l = 0; l < 4; l++) {
        inproj_k<<<dim3(16, 8), blk, 0, stream>>>(hb, winpb + (size_t)l * 1048576, ss + l * 1024, xr);
        conv_k<<<dim3(4096), blk, 0, stream>>>(xr, conv_w + (size_t)l * 4096, conv_b + l * 1024, xc, xcb);
        xpd_k<<<dim3(17, 8), blk, 0, stream>>>(xcb, wxpdb + (size_t)l * 1114112,
                                               dt_proj_b + l * 1024, xdbl, delta);
        scan_k<<<dim3(64), blk, 0, stream>>>(xc, delta, xdbl, A_log + (size_t)l * 16384,
                                             Dvec + l * 1024, xr, yb);
        outproj_k<<<dim3(4, 8), blk, 0, stream>>>(yb, woutpb + (size_t)l * 524288,
                                                  h, hb, ss + (l + 1) * 1024);
    }

    projf_k<<<dim3(16, 8), blk, 0, stream>>>(hb, wprojb, ss + 4096, xr);
    coeffs_k<<<dim3(1024), blk, 0, stream>>>(xr, inputs, coeffs, preds);
}

// Round 6
// 777.592 us; speedup vs baseline: 2.8968x; 1.0538x over previous
//
#include <hip/hip_runtime.h>
#include <hip/hip_bf16.h>
#include <math.h>

namespace {

constexpr int SEQ    = 64;
constexpr int DINNER = 1024;
constexpr int DFF    = 16;
constexpr int DTRANK = 32;

typedef __attribute__((ext_vector_type(8))) short short8;
typedef __attribute__((ext_vector_type(4))) float f32x4;
typedef __attribute__((address_space(3))) unsigned int lds_u32_t;
typedef __attribute__((address_space(1))) unsigned int glb_u32_t;

__device__ __forceinline__ float sigm(float x) { return 1.f / (1.f + __expf(-x)); }
__device__ __forceinline__ short f2b(float v) {
    __hip_bfloat16 h = __float2bfloat16(v);
    return *(short*)&h;
}
__device__ __forceinline__ float softp(float v) {
    return fmaxf(v, 0.f) + log1pf(__expf(-fabsf(v)));
}

// ================= bf16 MFMA GEMM core: BM=128 x BN, BK=32, 4 waves (2x2) ==========
template <int BN>
__device__ __forceinline__ void gemm_core(
    f32x4 (&acc)[4][BN / 32],
    const short* __restrict__ A, int lda,
    const short* __restrict__ W, int ldw,
    int Kd, short* As, short* Bs, int m0, int n0)
{
    constexpr int NFR = BN / 32;
    const int tid = threadIdx.x, wave = tid >> 6, lane = tid & 63;
    const int wm = wave >> 1, wn = wave & 1;
    const int l15 = lane & 15, kg = lane >> 4;

    const int pA0 = wave * 128 + lane, pA1 = pA0 + 64;
    const short* srcA0 = A + (size_t)(m0 + (pA0 >> 2)) * lda + (pA0 & 3) * 8;
    const short* srcA1 = A + (size_t)(m0 + (pA1 >> 2)) * lda + (pA1 & 3) * 8;
    short* ldsA0 = As + (size_t)(wave * 128) * 8;
    short* ldsA1 = As + (size_t)(wave * 128 + 64) * 8;

    const short* srcB0; const short* srcB1 = nullptr;
    short* ldsB0; short* ldsB1 = nullptr;
    if constexpr (BN == 128) {
        const int pB0 = wave * 128 + lane, pB1 = pB0 + 64;
        srcB0 = W + (size_t)(n0 + (pB0 >> 2)) * ldw + (pB0 & 3) * 8;
        srcB1 = W + (size_t)(n0 + (pB1 >> 2)) * ldw + (pB1 & 3) * 8;
        ldsB0 = Bs + (size_t)(wave * 128) * 8;
        ldsB1 = Bs + (size_t)(wave * 128 + 64) * 8;
    } else {
        const int pB0 = wave * 64 + lane;
        srcB0 = W + (size_t)(n0 + (pB0 >> 2)) * ldw + (pB0 & 3) * 8;
        ldsB0 = Bs + (size_t)(wave * 64) * 8;
    }

    for (int k0 = 0; k0 < Kd; k0 += 32) {
        __syncthreads();
        __builtin_amdgcn_global_load_lds((const glb_u32_t*)(srcA0 + k0), (lds_u32_t*)ldsA0, 16, 0, 0);
        __builtin_amdgcn_global_load_lds((const glb_u32_t*)(srcA1 + k0), (lds_u32_t*)ldsA1, 16, 0, 0);
        __builtin_amdgcn_global_load_lds((const glb_u32_t*)(srcB0 + k0), (lds_u32_t*)ldsB0, 16, 0, 0);
        if constexpr (BN == 128)
            __builtin_amdgcn_global_load_lds((const glb_u32_t*)(srcB1 + k0), (lds_u32_t*)ldsB1, 16, 0, 0);
        __syncthreads();

        short8 af[4], bfr[NFR];
#pragma unroll
        for (int mi = 0; mi < 4; mi++)
            af[mi] = *(const short8*)(As + (wm * 64 + mi * 16 + l15) * 32 + kg * 8);
#pragma unroll
        for (int ni = 0; ni < NFR; ni++)
            bfr[ni] = *(const short8*)(Bs + (wn * (BN / 2) + ni * 16 + l15) * 32 + kg * 8);
#pragma unroll
        for (int mi = 0; mi < 4; mi++)
#pragma unroll
            for (int ni = 0; ni < NFR; ni++)
                acc[mi][ni] = __builtin_amdgcn_mfma_f32_16x16x32_bf16(af[mi], bfr[ni], acc[mi][ni], 0, 0, 0);
    }
}
// C/D frag mapping [m89]: col = n0 + wn*(BN/2) + ni*16 + (lane&15);
//                         row = m0 + wm*64 + mi*16 + (lane>>4)*4 + j

// ================= prep: conversions (+gamma fold), W_delta, zeroing =================
__global__ __launch_bounds__(256) void prep_k(
    const float* __restrict__ lin1_w, const float* __restrict__ gate_w,
    const float* __restrict__ lin2_w, const float* __restrict__ in_proj_w,
    const float* __restrict__ out_proj_w, const float* __restrict__ proj_w,
    const float* __restrict__ x_proj_w, const float* __restrict__ dt_proj_w,
    const float* __restrict__ inputs, const float* __restrict__ blk_norm_w,
    const float* __restrict__ post_norm_w,
    short* __restrict__ wlin1gb, short* __restrict__ wlin2b, short* __restrict__ winpb,
    short* __restrict__ woutpb, short* __restrict__ wprojb, short* __restrict__ wxpdb,
    short* __restrict__ inputsb, float* __restrict__ preds, float* __restrict__ ss)
{
    const int blk = blockIdx.x, tid = threadIdx.x;
    if (blk < 1024) {
        // W_delta = dt_w(1024x32) @ xp_w[:32](32x1024), per layer; wave per n-row
        const int wave = tid >> 6, lane = tid & 63;
        const int nrow = blk * 4 + wave;          // 0..4095
        const int l = nrow >> 10, n = nrow & 1023;
        const float* dtw = dt_proj_w + (size_t)l * 32768 + n * 32;
        const float* xpw = x_proj_w + (size_t)l * 65536;
        float4 acc[4] = {};
        for (int r = 0; r < 32; r++) {
            const float s = dtw[r];
#pragma unroll
            for (int rep = 0; rep < 4; rep++) {
                const float4 xv = *(const float4*)(xpw + r * 1024 + rep * 256 + lane * 4);
                acc[rep].x = fmaf(s, xv.x, acc[rep].x);
                acc[rep].y = fmaf(s, xv.y, acc[rep].y);
                acc[rep].z = fmaf(s, xv.z, acc[rep].z);
                acc[rep].w = fmaf(s, xv.w, acc[rep].w);
            }
        }
        short* dst = wxpdb + (size_t)l * 1114112 + (size_t)(64 + n) * 1024;
#pragma unroll
        for (int rep = 0; rep < 4; rep++) {
            union { short sh[4]; uint2 u; } pk;
            pk.sh[0] = f2b(acc[rep].x); pk.sh[1] = f2b(acc[rep].y);
            pk.sh[2] = f2b(acc[rep].z); pk.sh[3] = f2b(acc[rep].w);
            *(uint2*)(dst + rep * 256 + lane * 4) = pk.u;
        }
    } else if (blk < 1088) {
#pragma unroll
        for (int rep = 0; rep < 4; rep++) {
            const int e = (blk - 1024) * 4096 + rep * 1024 + tid * 4;  // < 262144
            const int l = e >> 16, rowk = e & 65535;
            const float4 v = *(const float4*)(x_proj_w + (size_t)l * 65536 + rowk);
            union { short sh[4]; uint2 u; } pk;
            pk.sh[0] = f2b(v.x); pk.sh[1] = f2b(v.y); pk.sh[2] = f2b(v.z); pk.sh[3] = f2b(v.w);
            *(uint2*)(wxpdb + (size_t)l * 1114112 + rowk) = pk.u;
        }
    } else if (blk < 2048) {
        constexpr int pre[8] = {0, 128, 256, 512, 4608, 6656, 7680, 7936};
        for (int vb = blk - 1088; vb < 7936; vb += 960) {
            int s = 0;
#pragma unroll
            for (int i = 1; i < 7; i++) s += (vb >= pre[i]);
            const int e = (vb - pre[s]) * 1024 + tid * 4;
            const float* src; short* dst;
            bool hasG = false; const float* gp = nullptr;
            if      (s == 0) { src = lin1_w + e;     dst = wlin1gb + e; }
            else if (s == 1) { src = gate_w + e;     dst = wlin1gb + 131072 + e; }
            else if (s == 2) { src = lin2_w + e;     dst = wlin2b + e; }
            else if (s == 3) { src = in_proj_w + e;  dst = winpb + e;
                               hasG = true; gp = blk_norm_w + (e >> 20) * 512 + (e & 511); }
            else if (s == 4) { src = out_proj_w + e; dst = woutpb + e; }
            else if (s == 5) { src = proj_w + e;     dst = wprojb + e;
                               hasG = true; gp = post_norm_w + (e & 511); }
            else             { src = inputs + e;     dst = inputsb + e; }
            float4 v = *(const float4*)src;
            if (hasG) {
                const float4 gv = *(const float4*)gp;
                v.x *= gv.x; v.y *= gv.y; v.z *= gv.z; v.w *= gv.w;
            }
            union { short sh[4]; uint2 u; } pk;
            pk.sh[0] = f2b(v.x); pk.sh[1] = f2b(v.y); pk.sh[2] = f2b(v.z); pk.sh[3] = f2b(v.w);
            *(uint2*)dst = pk.u;
        }
    } else {
        const int i = (blk - 2048) * 256 + tid;   // < 8192
        if (i < 4096) preds[i] = 0.f;
        else ss[1024 + (i - 4096)] = 0.f;          // zero ss slots 1..4
    }
}

// ================= spatial: lin1|gate merged (N=1024) =================
__global__ __launch_bounds__(256) void lin1gate_k(
    const short* __restrict__ A, const short* __restrict__ W,
    const float* __restrict__ b1, const float* __restrict__ b2,
    short* __restrict__ h1b, float* __restrict__ g)
{
    __shared__ short As[128 * 32];
    __shared__ short Bs[128 * 32];
    f32x4 acc[4][4] = {};
    const int m0 = blockIdx.y * 128, n0 = blockIdx.x * 128;
    gemm_core<128>(acc, A, 256, W, 256, 256, As, Bs, m0, n0);
    const int lane = threadIdx.x & 63, wave = threadIdx.x >> 6;
    const int wm = wave >> 1, wn = wave & 1, l15 = lane & 15, kg = lane >> 4;
#pragma unroll
    for (int ni = 0; ni < 4; ni++) {
        const int col = n0 + wn * 64 + ni * 16 + l15;
        const bool isG = col >= 512;
        const float b = isG ? b2[col - 512] : b1[col];
#pragma unroll
        for (int mi = 0; mi < 4; mi++)
#pragma unroll
            for (int j = 0; j < 4; j++) {
                const int row = m0 + wm * 64 + mi * 16 + kg * 4 + j;
                const float v = acc[mi][ni][j] + b;
                if (isG) g[(size_t)row * 512 + (col - 512)] = sigm(v);
                else     h1b[(size_t)row * 512 + col] = f2b(0.5f * v * (1.f + erff(v * 0.70710678f)));
            }
    }
}

// ================= lin2: x = (h1 @ W^T + b) * g =================
__global__ __launch_bounds__(256) void lin2_k(
    const short* __restrict__ A, const short* __restrict__ W,
    const float* __restrict__ bias, const float* __restrict__ g, float* __restrict__ x)
{
    __shared__ short As[128 * 32];
    __shared__ short Bs[128 * 32];
    f32x4 acc[4][4] = {};
    const int m0 = blockIdx.y * 128, n0 = blockIdx.x * 128;
    gemm_core<128>(acc, A, 512, W, 512, 512, As, Bs, m0, n0);
    const int lane = threadIdx.x & 63, wave = threadIdx.x >> 6;
    const int wm = wave >> 1, wn = wave & 1, l15 = lane & 15, kg = lane >> 4;
#pragma unroll
    for (int ni = 0; ni < 4; ni++) {
        const int col = n0 + wn * 64 + ni * 16 + l15;
        const float b = bias[col];
#pragma unroll
        for (int mi = 0; mi < 4; mi++)
#pragma unroll
            for (int j = 0; j < 4; j++) {
                const int row = m0 + wm * 64 + mi * 16 + kg * 4 + j;
                x[(size_t)row * 512 + col] = (acc[mi][ni][j] + b) * g[(size_t)row * 512 + col];
            }
    }
}

// ================= spatial rmsnorm: h fp32 + hb bf16 + ss[0] =================
__global__ __launch_bounds__(256) void rms_sp_k(
    const float* __restrict__ x, const float* __restrict__ w,
    float* __restrict__ h, short* __restrict__ hb, float* __restrict__ ss0)
{
    const int lane = threadIdx.x & 63;
    const int rowId = blockIdx.x * 4 + (threadIdx.x >> 6);
    const float* ip = x + (size_t)rowId * 512 + lane * 8;
    const float4 v1 = *(const float4*)ip;
    const float4 v2 = *(const float4*)(ip + 4);
    float sq = v1.x * v1.x + v1.y * v1.y + v1.z * v1.z + v1.w * v1.w
             + v2.x * v2.x + v2.y * v2.y + v2.z * v2.z + v2.w * v2.w;
#pragma unroll
    for (int off = 32; off > 0; off >>= 1) sq += __shfl_xor(sq, off, 64);
    const float rs = rsqrtf(sq * (1.f / 512.f) + 1e-5f);
    const float4 w1 = *(const float4*)(w + lane * 8);
    const float4 w2 = *(const float4*)(w + lane * 8 + 4);
    const float o[8] = { v1.x * rs * w1.x, v1.y * rs * w1.y, v1.z * rs * w1.z, v1.w * rs * w1.w,
                         v2.x * rs * w2.x, v2.y * rs * w2.y, v2.z * rs * w2.z, v2.w * rs * w2.w };
    float* op = h + (size_t)rowId * 512 + lane * 8;
    *(float4*)op       = make_float4(o[0], o[1], o[2], o[3]);
    *(float4*)(op + 4) = make_float4(o[4], o[5], o[6], o[7]);
    short8 pk;
#pragma unroll
    for (int i = 0; i < 8; i++) pk[i] = f2b(o[i]);
    *(short8*)(hb + (size_t)rowId * 512 + lane * 8) = pk;
    float s2 = 0.f;
#pragma unroll
    for (int i = 0; i < 8; i++) s2 = fmaf(o[i], o[i], s2);
#pragma unroll
    for (int off = 32; off > 0; off >>= 1) s2 += __shfl_xor(s2, off, 64);
    if (lane == 0) ss0[rowId] = s2;
}

// ================= in_proj + fused depthwise conv + silu =================
// Tile 128 rows (2 whole batches) x 128 cols. n0<1024: conv cols; n0>=1024: silu(res).
union ConvU {
    struct { short As[128 * 32]; short Bs[128 * 32]; } gm;   // 16 KB (GEMM phase)
    float cbuf[67][132];                                      // 35.4 KB (conv phase)
};

__global__ __launch_bounds__(256) void inprojconv_k(
    const short* __restrict__ A, const short* __restrict__ W,
    const float* __restrict__ ss_in, const float* __restrict__ cw,
    const float* __restrict__ cb, float* __restrict__ xc,
    short* __restrict__ xcb, float* __restrict__ sr)
{
    __shared__ ConvU u;
    f32x4 acc[4][4] = {};
    const int m0 = blockIdx.y * 128, n0 = blockIdx.x * 128;
    gemm_core<128>(acc, A, 512, W, 512, 512, u.gm.As, u.gm.Bs, m0, n0);
    const int tid = threadIdx.x;
    const int lane = tid & 63, wave = tid >> 6;
    const int wm = wave >> 1, wn = wave & 1, l15 = lane & 15, kg = lane >> 4;

    // rmsnorm row scale
#pragma unroll
    for (int mi = 0; mi < 4; mi++)
#pragma unroll
        for (int j = 0; j < 4; j++) {
            const int row = m0 + wm * 64 + mi * 16 + kg * 4 + j;
            const float r = rsqrtf(ss_in[row] * (1.f / 512.f) + 1e-5f);
#pragma unroll
            for (int ni = 0; ni < 4; ni++) acc[mi][ni][j] *= r;
        }

    if (n0 < 1024) {
        // ---- two-pass LDS conv over the tile (causal within each 64-row batch) ----
        const int ccol = tid & 127;        // fixed col per thread
        const int r0 = tid >> 7;           // 0/1
        const int d = n0 + ccol;
        const float4 w4 = *(const float4*)(cw + d * 4);
        const float bia = cb[d];

        __syncthreads();   // all waves done with As/Bs LDS (gemm)
        // pass 1: rows 0..63 (written by wm==0 waves) into slots 3..66; zero-pad slots 0..2
        if (wm == 0)
#pragma unroll
            for (int mi = 0; mi < 4; mi++)
#pragma unroll
                for (int ni = 0; ni < 4; ni++)
#pragma unroll
                    for (int j = 0; j < 4; j++)
                        u.cbuf[3 + mi * 16 + kg * 4 + j][wn * 64 + ni * 16 + l15] = acc[mi][ni][j];
        for (int i = tid; i < 384; i += 256) u.cbuf[i >> 7][i & 127] = 0.f;
        __syncthreads();
#pragma unroll 4
        for (int k = 0; k < 32; k++) {
            const int row = r0 + 2 * k;    // 0..63
            float v = bia + w4.x * u.cbuf[row][ccol] + w4.y * u.cbuf[row + 1][ccol]
                          + w4.z * u.cbuf[row + 2][ccol] + w4.w * u.cbuf[row + 3][ccol];
            v = v * sigm(v);
            const size_t idx = (size_t)(m0 + row) * 1024 + d;
            xc[idx] = v; xcb[idx] = f2b(v);
        }
        __syncthreads();
        // carry rows 61..63 (slots 64..66) into pad slots 0..2
        for (int i = tid; i < 384; i += 256) u.cbuf[i >> 7][i & 127] = u.cbuf[64 + (i >> 7)][i & 127];
        __syncthreads();
        // pass 2: rows 64..127 (wm==1 waves)
        if (wm == 1)
#pragma unroll
            for (int mi = 0; mi < 4; mi++)
#pragma unroll
                for (int ni = 0; ni < 4; ni++)
#pragma unroll
                    for (int j = 0; j < 4; j++)
                        u.cbuf[3 + mi * 16 + kg * 4 + j][wn * 64 + ni * 16 + l15] = acc[mi][ni][j];
        __syncthreads();
#pragma unroll 4
        for (int k = 0; k < 32; k++) {
            const int row = r0 + 2 * k;    // local 0..63 -> global row m0+64+row
            float v = bia + w4.x * u.cbuf[row][ccol] + w4.y * u.cbuf[row + 1][ccol]
                          + w4.z * u.cbuf[row + 2][ccol] + w4.w * u.cbuf[row + 3][ccol];
            v = v * sigm(v);
            const size_t idx = (size_t)(m0 + 64 + row) * 1024 + d;
            xc[idx] = v; xcb[idx] = f2b(v);
        }
    } else {
        // res half: store silu(res) directly
#pragma unroll
        for (int ni = 0; ni < 4; ni++) {
            const int scol = n0 - 1024 + wn * 64 + ni * 16 + l15;
#pragma unroll
            for (int mi = 0; mi < 4; mi++)
#pragma unroll
                for (int j = 0; j < 4; j++) {
                    const int row = m0 + wm * 64 + mi * 16 + kg * 4 + j;
                    const float v = acc[mi][ni][j];
                    sr[(size_t)row * 1024 + scol] = v * sigm(v);
                }
        }
    }
}

// ================= xpd: [xdbl | delta] = xcb @ [xpw; W_delta]^T (N=1088) =================
__global__ __launch_bounds__(256) void xpd_k(
    const short* __restrict__ A, const short* __restrict__ W,
    const float* __restrict__ dtb, float* __restrict__ xdbl, float* __restrict__ delta)
{
    __shared__ short As[128 * 32];
    __shared__ short Bs[64 * 32];
    f32x4 acc[4][2] = {};
    const int m0 = blockIdx.y * 128, n0 = blockIdx.x * 64;
    gemm_core<64>(acc, A, 1024, W, 1024, 1024, As, Bs, m0, n0);
    const int lane = threadIdx.x & 63, wave = threadIdx.x >> 6;
    const int wm = wave >> 1, wn = wave & 1, l15 = lane & 15, kg = lane >> 4;
#pragma unroll
    for (int ni = 0; ni < 2; ni++) {
        const int col = n0 + wn * 32 + ni * 16 + l15;
#pragma unroll
        for (int mi = 0; mi < 4; mi++)
#pragma unroll
            for (int j = 0; j < 4; j++) {
                const int row = m0 + wm * 64 + mi * 16 + kg * 4 + j;
                const float v = acc[mi][ni][j];
                if (col < 64) xdbl[(size_t)row * 64 + col] = v;
                else          delta[(size_t)row * 1024 + (col - 64)] = softp(v + dtb[col - 64]);
            }
    }
}

// ================= scan: 256 blocks x 64 thr (1 wave), reads precomputed silu(res) ====
__global__ __launch_bounds__(64) void scan_k(
    const float* __restrict__ xc, const float* __restrict__ delta,
    const float* __restrict__ xdbl, const float* __restrict__ Alog,
    const float* __restrict__ Dp, const float* __restrict__ sr, short* __restrict__ yb)
{
    const int b = blockIdx.x >> 4;
    const int d = ((blockIdx.x & 15) << 6) + threadIdx.x;
    __shared__ float Bsh[SEQ][DFF];
    __shared__ float Csh[SEQ][DFF];
    for (int i = threadIdx.x; i < SEQ * DFF; i += 64) {
        const int l = i >> 4, n = i & 15;
        Bsh[l][n] = xdbl[(size_t)(b * SEQ + l) * 64 + DTRANK + n];
        Csh[l][n] = xdbl[(size_t)(b * SEQ + l) * 64 + DTRANK + DFF + n];
    }
    __syncthreads();
    float a[16], s[16];
#pragma unroll
    for (int n = 0; n < 16; n++) { a[n] = -__expf(Alog[(size_t)d * 16 + n]); s[n] = 0.f; }
    const float dv = Dp[d];
    for (int l = 0; l < SEQ; l++) {
        const size_t m = (size_t)b * SEQ + l;
        const float dlt = delta[m * DINNER + d];
        const float u = xc[m * DINNER + d];
        const float dbu = dlt * u;
        float acc = 0.f;
#pragma unroll
        for (int n = 0; n < 16; n++) {
            s[n] = __expf(dlt * a[n]) * s[n] + dbu * Bsh[l][n];
            acc = fmaf(s[n], Csh[l][n], acc);
        }
        acc = fmaf(u, dv, acc);
        yb[m * DINNER + d] = f2b(acc * sr[m * 1024 + d]);
    }
}

// ================= out_proj: h += yb @ W^T; writes h fp32 + hb bf16 + ss_out =========
__global__ __launch_bounds__(256) void outproj_k(
    const short* __restrict__ A, const short* __restrict__ W,
    float* __restrict__ h, short* __restrict__ hb, float* __restrict__ ss_out)
{
    __shared__ short As[128 * 32];
    __shared__ short Bs[128 * 32];
    f32x4 acc[4][4] = {};
    const int m0 = blockIdx.y * 128, n0 = blockIdx.x * 128;
    gemm_core<128>(acc, A, 1024, W, 1024, 1024, As, Bs, m0, n0);
    const int lane = threadIdx.x & 63, wave = threadIdx.x >> 6;
    const int wm = wave >> 1, wn = wave & 1, l15 = lane & 15, kg = lane >> 4;
    float vsq[4][4] = {};
#pragma unroll
    for (int ni = 0; ni < 4; ni++) {
        const int col = n0 + wn * 64 + ni * 16 + l15;
#pragma unroll
        for (int mi = 0; mi < 4; mi++)
#pragma unroll
            for (int j = 0; j < 4; j++) {
                const int row = m0 + wm * 64 + mi * 16 + kg * 4 + j;
                const float v = acc[mi][ni][j] + h[(size_t)row * 512 + col];
                h[(size_t)row * 512 + col] = v;
                hb[(size_t)row * 512 + col] = f2b(v);
                vsq[mi][j] = fmaf(v, v, vsq[mi][j]);
            }
    }
#pragma unroll
    for (int mi = 0; mi < 4; mi++)
#pragma unroll
        for (int j = 0; j < 4; j++) {
            float t = vsq[mi][j];
            t += __shfl_xor(t, 1, 64);
            t += __shfl_xor(t, 2, 64);
            t += __shfl_xor(t, 4, 64);
            t += __shfl_xor(t, 8, 64);
            if (l15 == 0) {
                const int row = m0 + wm * 64 + mi * 16 + kg * 4 + j;
                atomicAdd(ss_out + row, t);
            }
        }
}

// ================= final proj: xr = r[row] * (hb @ (W.gamma)^T) =================
__global__ __launch_bounds__(256) void projf_k(
    const short* __restrict__ A, const short* __restrict__ W,
    const float* __restrict__ ss_in, float* __restrict__ xr)
{
    __shared__ short As[128 * 32];
    __shared__ short Bs[128 * 32];
    f32x4 acc[4][4] = {};
    const int m0 = blockIdx.y * 128, n0 = blockIdx.x * 128;
    gemm_core<128>(acc, A, 512, W, 512, 512, As, Bs, m0, n0);
    const int lane = threadIdx.x & 63, wave = threadIdx.x >> 6;
    const int wm = wave >> 1, wn = wave & 1, l15 = lane & 15, kg = lane >> 4;
#pragma unroll
    for (int mi = 0; mi < 4; mi++)
#pragma unroll
        for (int j = 0; j < 4; j++) {
            const int row = m0 + wm * 64 + mi * 16 + kg * 4 + j;
            const float r = rsqrtf(ss_in[row] * (1.f / 512.f) + 1e-5f);
#pragma unroll
            for (int ni = 0; ni < 4; ni++) {
                const int col = n0 + wn * 64 + ni * 16 + l15;
                xr[(size_t)row * 2048 + col] = acc[mi][ni][j] * r;
            }
        }
}

// ================= coeffs + preds =================
__global__ __launch_bounds__(256) void coeffs_k(
    const float* __restrict__ outp, const float* __restrict__ inp,
    float* __restrict__ coeffs, float* __restrict__ preds)
{
    const int m = blockIdx.x;
    const int b = m >> 6;
    const int tid = threadIdx.x, wave = tid >> 6, lane = tid & 63;
    __shared__ float4 Us[256], Vs[256];
    __shared__ float ins[256];
    __shared__ float4 tpart[4];
    Us[tid] = *(const float4*)(outp + (size_t)m * 2048 + tid * 4);
    Vs[tid] = *(const float4*)(outp + (size_t)m * 2048 + 1024 + tid * 4);
    ins[tid] = inp[(size_t)m * 256 + tid];
    __syncthreads();
    const float4 vq0 = Vs[lane * 4 + 0], vq1 = Vs[lane * 4 + 1];
    const float4 vq2 = Vs[lane * 4 + 2], vq3 = Vs[lane * 4 + 3];
    float* cbase = coeffs + (size_t)m * 65536 + lane * 4;
#pragma unroll 4
    for (int i = 0; i < 64; i++) {
        const int pp = (wave << 6) + i;
        const float4 up = Us[pp];
        float4 c;
        c.x = up.x * vq0.x + up.y * vq0.y + up.z * vq0.z + up.w * vq0.w;
        c.y = up.x * vq1.x + up.y * vq1.y + up.z * vq1.z + up.w * vq1.w;
        c.z = up.x * vq2.x + up.y * vq2.y + up.z * vq2.z + up.w * vq2.w;
        c.w = up.x * vq3.x + up.y * vq3.y + up.z * vq3.z + up.w * vq3.w;
        *(float4*)(cbase + (size_t)pp * 256) = c;
    }
    const float iv = ins[tid];
    const float4 vm = Vs[tid];
    float4 t = make_float4(vm.x * iv, vm.y * iv, vm.z * iv, vm.w * iv);
#pragma unroll
    for (int off = 32; off > 0; off >>= 1) {
        t.x += __shfl_xor(t.x, off, 64);
        t.y += __shfl_xor(t.y, off, 64);
        t.z += __shfl_xor(t.z, off, 64);
        t.w += __shfl_xor(t.w, off, 64);
    }
    if (lane == 0) tpart[wave] = t;
    __syncthreads();
    const float4 t0 = tpart[0], t1 = tpart[1], t2 = tpart[2], t3 = tpart[3];
    const float4 tt = make_float4(t0.x + t1.x + t2.x + t3.x, t0.y + t1.y + t2.y + t3.y,
                                  t0.z + t1.z + t2.z + t3.z, t0.w + t1.w + t2.w + t3.w);
    const float4 up = Us[tid];
    const float pv = up.x * tt.x + up.y * tt.y + up.z * tt.z + up.w * tt.w;
    atomicAdd(preds + (size_t)b * 256 + tid, pv);
}

} // namespace

extern "C" void kernel_launch(void* const* d_in, const int* in_sizes, int n_in,
                              void* d_out, int out_size, void* d_ws, size_t ws_size,
                              hipStream_t stream)
{
    const float* inputs     = (const float*)d_in[0];
    const float* lin1_w     = (const float*)d_in[1];
    const float* lin1_b     = (const float*)d_in[2];
    const float* lin2_w     = (const float*)d_in[3];
    const float* lin2_b     = (const float*)d_in[4];
    const float* gate_w     = (const float*)d_in[5];
    const float* gate_b     = (const float*)d_in[6];
    const float* sp_norm_w  = (const float*)d_in[7];
    const float* in_proj_w  = (const float*)d_in[8];
    const float* conv_w     = (const float*)d_in[9];
    const float* conv_b     = (const float*)d_in[10];
    const float* x_proj_w   = (const float*)d_in[11];
    const float* dt_proj_w  = (const float*)d_in[12];
    const float* dt_proj_b  = (const float*)d_in[13];
    const float* A_log      = (const float*)d_in[14];
    const float* Dvec       = (const float*)d_in[15];
    const float* out_proj_w = (const float*)d_in[16];
    const float* blk_norm_w = (const float*)d_in[17];
    const float* post_norm_w= (const float*)d_in[18];
    const float* proj_w     = (const float*)d_in[19];

    float* ws = (float*)d_ws;
    // fp32 region
    float* h     = ws;                 // 1024 x 512
    float* xr    = ws + 524288;        // 1024 x 2048 (final proj out; first 1 M floats reused as sr during layers)
    float* sr    = xr;                 // 1024 x 1024 silu(res), overwritten by projf after layers
    float* x     = ws + 2621440;       // 1024 x 512 (lin2 out)
    float* g     = ws + 3145728;       // 1024 x 512
    float* delta = ws + 3670016;       // 1024 x 1024
    float* xc    = ws + 4718592;       // 1024 x 1024
    float* xdbl  = ws + 5767168;       // 1024 x 64
    float* ss    = ws + 5832704;       // 5 x 1024 sumsq slots
    // bf16 region
    short* bfb     = (short*)(ws + 5840896);
    short* inputsb = bfb;               // 1024 x 256
    short* h1b     = bfb + 262144;      // 1024 x 512
    short* hb      = bfb + 786432;      // 1024 x 512
    short* xcb     = bfb + 1310720;     // 1024 x 1024
    short* yb      = bfb + 2359296;     // 1024 x 1024
    short* wlin1gb = bfb + 3407872;     // 1024 x 256
    short* wlin2b  = bfb + 3670016;     // 512 x 512
    short* winpb   = bfb + 3932160;     // 4 x 2048 x 512 (gamma-folded)
    short* woutpb  = bfb + 8126464;     // 4 x 512 x 1024
    short* wprojb  = bfb + 10223616;    // 2048 x 512 (gamma-folded)
    short* wxpdb   = bfb + 11272192;    // 4 x 1088 x 1024 ([xpw; W_delta])
    float* preds  = (float*)d_out;
    float* coeffs = (float*)d_out + 4096;

    const dim3 blk(256);

    prep_k<<<dim3(2080), blk, 0, stream>>>(
        lin1_w, gate_w, lin2_w, in_proj_w, out_proj_w, proj_w, x_proj_w, dt_proj_w,
        inputs, blk_norm_w, post_norm_w,
        wlin1gb, wlin2b, winpb, woutpb, wprojb, wxpdb, inputsb, preds, ss);

    lin1gate_k<<<dim3(8, 8), blk, 0, stream>>>(inputsb, wlin1gb, lin1_b, gate_b, h1b, g);
    lin2_k<<<dim3(4, 8), blk, 0, stream>>>(h1b, wlin2b, lin2_b, g, x);
    rms_sp_k<<<dim3(256), blk, 0, stream>>>(x, sp_norm_w, h, hb, ss);

    for (int l = 0; l < 4; l++) {
        inprojconv_k<<<dim3(16, 8), blk, 0, stream>>>(
            hb, winpb + (size_t)l * 1048576, ss + l * 1024,
            conv_w + (size_t)l * 4096, conv_b + l * 1024, xc, xcb, sr);
        xpd_k<<<dim3(17, 8), blk, 0, stream>>>(xcb, wxpdb + (size_t)l * 1114112,
                                               dt_proj_b + l * 1024, xdbl, delta);
        scan_k<<<dim3(256), dim3(64), 0, stream>>>(xc, delta, xdbl, A_log + (size_t)l * 16384,
                                                   Dvec + l * 1024, sr, yb);
        outproj_k<<<dim3(4, 8), blk, 0, stream>>>(yb, woutpb + (size_t)l * 524288,
                                                  h, hb, ss + (l + 1) * 1024);
    }

    projf_k<<<dim3(16, 8), blk, 0, stream>>>(hb, wprojb, ss + 4096, xr);
    coeffs_k<<<dim3(1024), blk, 0, stream>>>(xr, inputs, coeffs, preds);
}